// Round 14
// baseline (824.715 us; speedup 1.0000x reference)
//
#include <hip/hip_runtime.h>
#include <hip/hip_bf16.h>
#include <math.h>

typedef __attribute__((ext_vector_type(8))) short bf16x8;
typedef __attribute__((ext_vector_type(4))) float f32x4;

typedef void __attribute__((address_space(1))) gvoid_t;
typedef void __attribute__((address_space(3))) lvoid_t;

#define KP0   1856          // 29 fields x 64
#define NB    16384
#define PBLK  128           // producer blocks (rest of 256 start as workers)
// workspace layout (bytes)
#define OFF_X    0u          // 16384*1856*2
#define OFF_H0   60817408u   // +16384*1024*2
#define OFF_W0T  94371840u   // +1856*1024*2
#define OFF_W1T  98172928u   // +1024*512*2
#define OFF_FM   99221504u   // 16384*4
#define OFF_NN   99287040u   // 16384*4
#define OFF_FLAG 99352576u   // 128 flags + ticket (ints)

#define VMCNT(n) asm volatile("s_waitcnt vmcnt(" #n ")" ::: "memory")
#define SBAR0()  __builtin_amdgcn_sched_barrier(0)

__device__ __forceinline__ float bf2f(short s) {
    return __uint_as_float(((unsigned)(unsigned short)s) << 16);
}

__device__ __forceinline__ void load_lds16(const void* g, void* l) {
    __builtin_amdgcn_global_load_lds(
        (gvoid_t*)(uintptr_t)g,
        (lvoid_t*)(unsigned)(uintptr_t)l,
        16, 0, 0);
}

// ==================== prep: W0T/W1T transposes + NN/flags zero
__device__ __forceinline__ void transpose_tile(const float* __restrict__ W,
                                               __hip_bfloat16* __restrict__ WT,
                                               int K, int N, int KP, int k0, int n0,
                                               float (*tile)[33], int tid) {
    const int tx = tid & 31, ty = tid >> 5;
    #pragma unroll
    for (int i = 0; i < 32; i += 8) {
        int k = k0 + ty + i;
        tile[ty + i][tx] = (k < K) ? W[(size_t)k * N + (n0 + tx)] : 0.f;
    }
    __syncthreads();
    #pragma unroll
    for (int i = 0; i < 32; i += 8) {
        int n = n0 + ty + i, k = k0 + tx;
        WT[(size_t)n * KP + k] = __float2bfloat16(tile[tx][ty + i]);
    }
}

__global__ __launch_bounds__(256) void prep(const float* __restrict__ w0,
                                            const float* __restrict__ w1,
                                            __hip_bfloat16* __restrict__ W0T,
                                            __hip_bfloat16* __restrict__ W1T,
                                            float* __restrict__ NN,
                                            int* __restrict__ FLG) {
    __shared__ float tile[32][33];
    const int b = blockIdx.x, tid = threadIdx.x;
    if (b < 1856) {
        transpose_tile(w0, W0T, 1805, 1024, KP0, (b % 58) * 32, (b / 58) * 32, tile, tid);
    } else if (b < 2368) {
        int bb = b - 1856;
        transpose_tile(w1, W1T, 1024, 512, 1024, (bb % 32) * 32, (bb / 32) * 32, tile, tid);
    } else {
        int r = (b - 2368) * 256 + tid;
        NN[r] = 0.f;
        if (b == 2368 && tid <= 128) FLG[tid] = 0;   // 128 flags + ticket
    }
}

// ==================== fused gather + gemm0 (producer/consumer, 256 blocks x 512)
// bid<PBLK: producer — wave-per-row gather, FLAT LOAD-PHASE into 66 DISTINCT
//   registers (v[26],m0[20],m1[20], never rewritten while stores pend), then ONE
//   sched_barrier(0), then consume/store phase. R13's failure was bufA reuse:
//   a VMEM store holds its data reg until completion (same in-order vmcnt as
//   loads), so re-filling the buffer waited on the stores AND all younger loads.
//   Here nothing is rewritten before the per-row vmcnt(0) drain -> 66 loads in
//   flight per wave. Per row: drain + release FLG[row>>7]+=1 (target 128).
// workers: ticket queue over 512 tiles (BM=128,BN=256), spin-acquire FLG[br]==128,
//   single-barrier double-buffered gemm (R8/R10-R13-proven body).
// LDS 96KB -> 1 block/CU, grid 256 = #CUs -> all co-resident (no deadlock).
__global__ __launch_bounds__(512, 2) void fused_g0(const int* __restrict__ oh,
                                                   const int* __restrict__ mh,
                                                   const float* __restrict__ fmw,
                                                   const float* __restrict__ emb,
                                                   const float* __restrict__ dense,
                                                   const __hip_bfloat16* __restrict__ W0T,
                                                   const float* __restrict__ b0,
                                                   __hip_bfloat16* __restrict__ X,
                                                   __hip_bfloat16* __restrict__ H0,
                                                   float* __restrict__ FM,
                                                   int* __restrict__ FLG) {
    __shared__ __align__(16) char lds[98304];      // A[2]:32K + B[2]:64K
    __shared__ int tau_sh;
    const int tid = threadIdx.x, bid = blockIdx.x;
    const int lane = tid & 63, wvi = tid >> 6;
    int* tick = FLG + 128;

    if (bid < PBLK) {
        // ---------------- producer role: flat load-phase / fence / store-phase
        const int gw = bid * 8 + wvi;              // 0..1023
        int ohi = (lane < 26) ? oh[gw * 26 + lane] : 0;
        int mhi = (lane < 40) ? mh[gw * 40 + lane] : 0;

        for (int row = gw; row < NB; row += PBLK * 8) {
            const int nrow = row + PBLK * 8;
            int ohiN = 0, mhiN = 0;
            if (nrow < NB) {
                ohiN = (lane < 26) ? oh[nrow * 26 + lane] : 0;
                mhiN = (lane < 40) ? mh[nrow * 40 + lane] : 0;
            }
            const float fm1 = (lane < 26) ? fmw[ohi] : 0.f;
            const float dv = (lane < 13) ? dense[row * 13 + lane] : 0.f;

            // ---- load phase: 66 gathers into 66 distinct registers
            float v[26], m0[20], m1[20];
            #pragma unroll
            for (int f = 0; f < 26; ++f) {
                int idx = __shfl(ohi, f);
                v[f] = emb[(size_t)idx * 64 + lane];
            }
            #pragma unroll
            for (int l = 0; l < 20; ++l) {
                int idx = __shfl(mhi, l);
                m0[l] = emb[(size_t)idx * 64 + lane];
            }
            #pragma unroll
            for (int l = 0; l < 20; ++l) {
                int idx = __shfl(mhi, 20 + l);
                m1[l] = emb[(size_t)idx * 64 + lane];
            }
            SBAR0();   // hard fence: no load sinks below, no store hoists above

            // ---- consume/store phase
            __hip_bfloat16* Xr = X + (size_t)row * KP0;
            float s = 0.f, sq = 0.f;
            #pragma unroll
            for (int f = 0; f < 26; ++f) {
                s += v[f]; sq += v[f] * v[f];
                Xr[f * 64 + lane] = __float2bfloat16(v[f]);
            }
            float a0 = 0.f, a1 = 0.f;
            #pragma unroll
            for (int l = 0; l < 20; ++l) { a0 += m0[l]; a1 += m1[l]; }
            a0 *= 0.05f; a1 *= 0.05f;
            s += a0 + a1; sq += a0 * a0 + a1 * a1;
            Xr[26 * 64 + lane] = __float2bfloat16(a0);
            Xr[27 * 64 + lane] = __float2bfloat16(a1);
            float red = 0.5f * (s * s - sq) + fm1;
            #pragma unroll
            for (int off = 32; off; off >>= 1) red += __shfl_xor(red, off);
            if (lane == 0) FM[row] = red;
            Xr[1792 + lane] = __float2bfloat16(dv);   // 1792..1855: dense + pad
            VMCNT(0);                                  // drain X stores
            if (lane == 0)
                __hip_atomic_fetch_add(&FLG[row >> 7], 1, __ATOMIC_RELEASE,
                                       __HIP_MEMORY_SCOPE_AGENT);
            ohi = ohiN; mhi = mhiN;
        }
    }

    // ---------------- worker role: gemm0 tiles off the ticket queue
    const int lr = lane & 15, lg = lane >> 4;
    const int wr = wvi >> 2, wc = wvi & 3;
    const int srcx = ((tid & 7) ^ ((tid >> 3) & 7)) << 4;
    const int xr0 = (lg ^ (lr & 7)) << 4;
    const int xr1 = ((4 + lg) ^ (lr & 7)) << 4;
    const int arow = (wr * 64 + lr) * 128;
    const int brow = (wc * 64 + lr) * 128;
    const float bv = b0[0];

    while (true) {
        if (tid == 0)
            tau_sh = __hip_atomic_fetch_add(tick, 1, __ATOMIC_RELAXED, __HIP_MEMORY_SCOPE_AGENT);
        __syncthreads();
        const int tau = tau_sh;
        __syncthreads();
        if (tau >= 512) break;
        const int tbr = tau >> 2, tbc = tau & 3;
        if (tid == 0) {
            while (__hip_atomic_load(&FLG[tbr], __ATOMIC_ACQUIRE, __HIP_MEMORY_SCOPE_AGENT) < 128)
                __builtin_amdgcn_s_sleep(2);
        }
        __syncthreads();   // all waves see fresh X; LDS safe vs previous tile

        const char* Ab = (const char*)X + (size_t)(tbr * 128) * (KP0 * 2);
        const char* Bb = (const char*)W0T + (size_t)(tbc * 256) * (KP0 * 2);
        auto stA = [&](int tt, int c) {
            int gr = c * 64 + (tid >> 3);
            load_lds16(Ab + (size_t)gr * (KP0 * 2) + (size_t)tt * 128 + srcx,
                       &lds[(tt & 1) * 16384 + c * 8192 + wvi * 1024]);
        };
        auto stB = [&](int tt, int c) {
            int gr = c * 64 + (tid >> 3);
            load_lds16(Bb + (size_t)gr * (KP0 * 2) + (size_t)tt * 128 + srcx,
                       &lds[32768 + (tt & 1) * 32768 + c * 8192 + wvi * 1024]);
        };

        f32x4 acc[4][4] = {};

        stA(0, 0); stA(0, 1);
        stB(0, 0); stB(0, 1); stB(0, 2); stB(0, 3);
        VMCNT(0);
        SBAR0();
        __builtin_amdgcn_s_barrier();

        for (int t = 0; t < 29; ++t) {
            if (t + 1 < 29) {
                stA(t + 1, 0); stA(t + 1, 1);
                stB(t + 1, 0); stB(t + 1, 1); stB(t + 1, 2); stB(t + 1, 3);
            }
            SBAR0();
            const char* LA = &lds[(t & 1) * 16384];
            const char* LB = &lds[32768 + (t & 1) * 32768];
            bf16x8 a[4][2], b[4][2];
            #pragma unroll
            for (int m = 0; m < 4; ++m) {
                a[m][0] = *(const bf16x8*)(LA + arow + m * 2048 + xr0);
                a[m][1] = *(const bf16x8*)(LA + arow + m * 2048 + xr1);
            }
            #pragma unroll
            for (int n = 0; n < 2; ++n) {
                b[n][0] = *(const bf16x8*)(LB + brow + n * 2048 + xr0);
                b[n][1] = *(const bf16x8*)(LB + brow + n * 2048 + xr1);
            }
            __builtin_amdgcn_s_setprio(1);
            #pragma unroll
            for (int m = 0; m < 4; ++m)
                #pragma unroll
                for (int n = 0; n < 2; ++n)
                    #pragma unroll
                    for (int kk = 0; kk < 2; ++kk)
                        acc[m][n] = __builtin_amdgcn_mfma_f32_16x16x32_bf16(a[m][kk], b[n][kk], acc[m][n], 0, 0, 0);
            __builtin_amdgcn_s_setprio(0);
            #pragma unroll
            for (int n = 2; n < 4; ++n) {
                b[n][0] = *(const bf16x8*)(LB + brow + n * 2048 + xr0);
                b[n][1] = *(const bf16x8*)(LB + brow + n * 2048 + xr1);
            }
            __builtin_amdgcn_s_setprio(1);
            #pragma unroll
            for (int m = 0; m < 4; ++m)
                #pragma unroll
                for (int n = 2; n < 4; ++n)
                    #pragma unroll
                    for (int kk = 0; kk < 2; ++kk)
                        acc[m][n] = __builtin_amdgcn_mfma_f32_16x16x32_bf16(a[m][kk], b[n][kk], acc[m][n], 0, 0, 0);
            __builtin_amdgcn_s_setprio(0);
            SBAR0();
            if (t + 1 < 29) {
                VMCNT(0);
                __builtin_amdgcn_s_barrier();
            }
        }

        const int rowb = tbr * 128 + wr * 64, colb = tbc * 256 + wc * 64;
        #pragma unroll
        for (int m = 0; m < 4; ++m)
            #pragma unroll
            for (int n = 0; n < 4; ++n)
                #pragma unroll
                for (int r = 0; r < 4; ++r) {
                    int row = rowb + m * 16 + lg * 4 + r;
                    int col = colb + n * 16 + lr;
                    H0[(size_t)row * 1024 + col] = __float2bfloat16(fmaxf(acc[m][n][r] + bv, 0.f));
                }
    }
}

// ==================== GEMM1 (single-barrier db, fused w2 dot) — R8 proven
template<int NREP, bool FUSED>
__global__ __launch_bounds__(512, 2) void gemm_db(const __hip_bfloat16* __restrict__ A,
                                                  const __hip_bfloat16* __restrict__ BT,
                                                  const float* __restrict__ bias,
                                                  __hip_bfloat16* __restrict__ C,
                                                  const float* __restrict__ w2,
                                                  float* __restrict__ NN,
                                                  int M, int N, int K) {
    constexpr int BREG = NREP * 8192;
    constexpr int NLO  = (NREP == 4) ? 2 : 1;
    __shared__ __align__(16) char lds[65536 + 2 * BREG];

    const int tid = threadIdx.x;
    const int wv = tid >> 6, lane = tid & 63;
    const int lr = lane & 15, lg = lane >> 4;
    const int wr = wv >> 2, wc = wv & 3;

    const int bid = blockIdx.x;
    const int wg = (bid & 7) * 32 + (bid >> 3);
    const int br = wg >> 2, bc = wg & 3;

    const size_t rowBytes = (size_t)K * 2;
    const char* Ab = (const char*)A + (size_t)(br * 256) * rowBytes;
    const char* Bb = (const char*)BT + (size_t)(bc * (NREP * 64)) * rowBytes;
    const int nt = K >> 6;

    const int srcx = ((tid & 7) ^ ((tid >> 3) & 7)) << 4;
    auto stA = [&](int tt, int c) {
        int gr = c * 64 + (tid >> 3);
        load_lds16(Ab + (size_t)gr * rowBytes + (size_t)tt * 128 + srcx,
                   &lds[(tt & 1) * 32768 + c * 8192 + wv * 1024]);
    };
    auto stB = [&](int tt, int c) {
        int gr = c * 64 + (tid >> 3);
        load_lds16(Bb + (size_t)gr * rowBytes + (size_t)tt * 128 + srcx,
                   &lds[65536 + (tt & 1) * BREG + c * 8192 + wv * 1024]);
    };

    f32x4 acc[8][NREP] = {};

    #pragma unroll
    for (int c = 0; c < 4; ++c) stA(0, c);
    #pragma unroll
    for (int c = 0; c < NREP; ++c) stB(0, c);
    VMCNT(0);
    SBAR0();
    __builtin_amdgcn_s_barrier();

    const int xr0 = (lg ^ (lr & 7)) << 4;
    const int xr1 = ((4 + lg) ^ (lr & 7)) << 4;
    const int arow = (wr * 128 + lr) * 128;
    const int brow = (wc * (NREP * 16) + lr) * 128;

    for (int t = 0; t < nt; ++t) {
        if (t + 1 < nt) {
            #pragma unroll
            for (int c = 0; c < 4; ++c) stA(t + 1, c);
            #pragma unroll
            for (int c = 0; c < NREP; ++c) stB(t + 1, c);
        }
        SBAR0();

        const char* LA = &lds[(t & 1) * 32768];
        const char* LB = &lds[65536 + (t & 1) * BREG];
        bf16x8 a1[4][2], a2[4][2], bl[NLO][2], bh[NLO][2];

        #pragma unroll
        for (int m = 0; m < 4; ++m) {
            a1[m][0] = *(const bf16x8*)(LA + arow + m * 2048 + xr0);
            a1[m][1] = *(const bf16x8*)(LA + arow + m * 2048 + xr1);
        }
        #pragma unroll
        for (int n = 0; n < NLO; ++n) {
            bl[n][0] = *(const bf16x8*)(LB + brow + n * 2048 + xr0);
            bl[n][1] = *(const bf16x8*)(LB + brow + n * 2048 + xr1);
        }
        __builtin_amdgcn_s_setprio(1);
        #pragma unroll
        for (int m = 0; m < 4; ++m)
            #pragma unroll
            for (int n = 0; n < NLO; ++n)
                #pragma unroll
                for (int kk = 0; kk < 2; ++kk)
                    acc[m][n] = __builtin_amdgcn_mfma_f32_16x16x32_bf16(a1[m][kk], bl[n][kk], acc[m][n], 0, 0, 0);
        __builtin_amdgcn_s_setprio(0);

        #pragma unroll
        for (int m = 0; m < 4; ++m) {
            a2[m][0] = *(const bf16x8*)(LA + arow + (4 + m) * 2048 + xr0);
            a2[m][1] = *(const bf16x8*)(LA + arow + (4 + m) * 2048 + xr1);
        }
        __builtin_amdgcn_s_setprio(1);
        #pragma unroll
        for (int m = 0; m < 4; ++m)
            #pragma unroll
            for (int n = 0; n < NLO; ++n)
                #pragma unroll
                for (int kk = 0; kk < 2; ++kk)
                    acc[4 + m][n] = __builtin_amdgcn_mfma_f32_16x16x32_bf16(a2[m][kk], bl[n][kk], acc[4 + m][n], 0, 0, 0);
        __builtin_amdgcn_s_setprio(0);

        #pragma unroll
        for (int n = 0; n < NLO; ++n) {
            bh[n][0] = *(const bf16x8*)(LB + brow + (NLO + n) * 2048 + xr0);
            bh[n][1] = *(const bf16x8*)(LB + brow + (NLO + n) * 2048 + xr1);
        }
        __builtin_amdgcn_s_setprio(1);
        #pragma unroll
        for (int m = 0; m < 4; ++m)
            #pragma unroll
            for (int n = 0; n < NLO; ++n)
                #pragma unroll
                for (int kk = 0; kk < 2; ++kk)
                    acc[m][NLO + n] = __builtin_amdgcn_mfma_f32_16x16x32_bf16(a1[m][kk], bh[n][kk], acc[m][NLO + n], 0, 0, 0);
        __builtin_amdgcn_s_setprio(0);

        __builtin_amdgcn_s_setprio(1);
        #pragma unroll
        for (int m = 0; m < 4; ++m)
            #pragma unroll
            for (int n = 0; n < NLO; ++n)
                #pragma unroll
                for (int kk = 0; kk < 2; ++kk)
                    acc[4 + m][NLO + n] = __builtin_amdgcn_mfma_f32_16x16x32_bf16(a2[m][kk], bh[n][kk], acc[4 + m][NLO + n], 0, 0, 0);
        __builtin_amdgcn_s_setprio(0);

        SBAR0();
        if (t + 1 < nt) {
            VMCNT(0);
            __builtin_amdgcn_s_barrier();
        }
    }

    const float bv = bias[0];
    const int rowb = br * 256 + wr * 128, colb = bc * (NREP * 64) + wc * (NREP * 16);
    if constexpr (FUSED) {
        float w2v[NREP];
        #pragma unroll
        for (int n = 0; n < NREP; ++n) w2v[n] = w2[colb + n * 16 + lr];
        #pragma unroll
        for (int m = 0; m < 8; ++m)
            #pragma unroll
            for (int r = 0; r < 4; ++r) {
                float p = 0.f;
                #pragma unroll
                for (int n = 0; n < NREP; ++n)
                    p += fmaxf(acc[m][n][r] + bv, 0.f) * w2v[n];
                #pragma unroll
                for (int off = 8; off; off >>= 1) p += __shfl_xor(p, off);
                if (lr == 0)
                    atomicAdd(&NN[rowb + m * 16 + lg * 4 + r], p);
            }
    } else {
        #pragma unroll
        for (int m = 0; m < 8; ++m)
            #pragma unroll
            for (int n = 0; n < NREP; ++n)
                #pragma unroll
                for (int r = 0; r < 4; ++r) {
                    int row = rowb + m * 16 + lg * 4 + r;
                    int col = colb + n * 16 + lr;
                    C[(size_t)row * N + col] = __float2bfloat16(fmaxf(acc[m][n][r] + bv, 0.f));
                }
    }
}

// ==================== finish: out = sigmoid(FM + relu(NN + b2))
__global__ __launch_bounds__(256) void finish_k(const float* __restrict__ NN,
                                                const float* __restrict__ b2,
                                                const float* __restrict__ FM,
                                                float* __restrict__ out) {
    const int row = blockIdx.x * 256 + threadIdx.x;
    float v = fmaxf(NN[row] + b2[0], 0.f) + FM[row];
    out[row] = 1.f / (1.f + expf(-v));
}

extern "C" void kernel_launch(void* const* d_in, const int* in_sizes, int n_in,
                              void* d_out, int out_size, void* d_ws, size_t ws_size,
                              hipStream_t stream) {
    const float* dense    = (const float*)d_in[0];
    const int*   onehot   = (const int*)d_in[1];
    const int*   multihot = (const int*)d_in[2];
    const float* fm_w     = (const float*)d_in[3];
    const float* fm_emb   = (const float*)d_in[4];
    const float* w0       = (const float*)d_in[5];
    const float* b0       = (const float*)d_in[6];
    const float* w1       = (const float*)d_in[7];
    const float* b1       = (const float*)d_in[8];
    const float* w2       = (const float*)d_in[9];
    const float* b2       = (const float*)d_in[10];
    float* out = (float*)d_out;

    char* ws = (char*)d_ws;
    __hip_bfloat16* X   = (__hip_bfloat16*)(ws + OFF_X);
    __hip_bfloat16* H0  = (__hip_bfloat16*)(ws + OFF_H0);
    __hip_bfloat16* W0T = (__hip_bfloat16*)(ws + OFF_W0T);
    __hip_bfloat16* W1T = (__hip_bfloat16*)(ws + OFF_W1T);
    float*          FM  = (float*)(ws + OFF_FM);
    float*          NN  = (float*)(ws + OFF_NN);
    int*            FLG = (int*)(ws + OFF_FLAG);

    prep<<<2432, 256, 0, stream>>>(w0, w1, W0T, W1T, NN, FLG);
    fused_g0<<<256, 512, 0, stream>>>(onehot, multihot, fm_w, fm_emb, dense,
                                      W0T, b0, X, H0, FM, FLG);
    gemm_db<2, true><<<256, 512, 0, stream>>>(H0, W1T, b1, nullptr, w2, NN,
                                              NB, 512, 1024);
    finish_k<<<64, 256, 0, stream>>>(NN, b2, FM, out);
}

// Round 15
// 815.605 us; speedup vs baseline: 1.0112x; 1.0112x over previous
//
#include <hip/hip_runtime.h>
#include <hip/hip_bf16.h>
#include <math.h>

typedef __attribute__((ext_vector_type(8))) short bf16x8;
typedef __attribute__((ext_vector_type(4))) float f32x4;

typedef void __attribute__((address_space(1))) gvoid_t;
typedef void __attribute__((address_space(3))) lvoid_t;

#define KP0   1856          // 29 fields x 64
#define NB    16384
#define PBLK  128           // producer blocks (rest of 256 start as workers)
// workspace layout (bytes)
#define OFF_X    0u          // 16384*1856*2
#define OFF_H0   60817408u   // +16384*1024*2
#define OFF_W0T  94371840u   // +1856*1024*2
#define OFF_W1T  98172928u   // +1024*512*2
#define OFF_FM   99221504u   // 16384*4
#define OFF_NN   99287040u   // 16384*4
#define OFF_FLAG 99352576u   // 128 flags + ticket (ints)

#define VMCNT(n) asm volatile("s_waitcnt vmcnt(" #n ")" ::: "memory")
#define LGKM0()  asm volatile("s_waitcnt lgkmcnt(0)" ::: "memory")
#define SBAR0()  __builtin_amdgcn_sched_barrier(0)

__device__ __forceinline__ float bf2f(short s) {
    return __uint_as_float(((unsigned)(unsigned short)s) << 16);
}

__device__ __forceinline__ void load_lds16(const void* g, void* l) {
    __builtin_amdgcn_global_load_lds(
        (gvoid_t*)(uintptr_t)g,
        (lvoid_t*)(unsigned)(uintptr_t)l,
        16, 0, 0);
}

__device__ __forceinline__ void load_lds4(const void* g, void* l) {
    __builtin_amdgcn_global_load_lds(
        (gvoid_t*)(uintptr_t)g,
        (lvoid_t*)(unsigned)(uintptr_t)l,
        4, 0, 0);
}

// ==================== prep: W0T/W1T transposes + NN/flags zero
__device__ __forceinline__ void transpose_tile(const float* __restrict__ W,
                                               __hip_bfloat16* __restrict__ WT,
                                               int K, int N, int KP, int k0, int n0,
                                               float (*tile)[33], int tid) {
    const int tx = tid & 31, ty = tid >> 5;
    #pragma unroll
    for (int i = 0; i < 32; i += 8) {
        int k = k0 + ty + i;
        tile[ty + i][tx] = (k < K) ? W[(size_t)k * N + (n0 + tx)] : 0.f;
    }
    __syncthreads();
    #pragma unroll
    for (int i = 0; i < 32; i += 8) {
        int n = n0 + ty + i, k = k0 + tx;
        WT[(size_t)n * KP + k] = __float2bfloat16(tile[tx][ty + i]);
    }
}

__global__ __launch_bounds__(256) void prep(const float* __restrict__ w0,
                                            const float* __restrict__ w1,
                                            __hip_bfloat16* __restrict__ W0T,
                                            __hip_bfloat16* __restrict__ W1T,
                                            float* __restrict__ NN,
                                            int* __restrict__ FLG) {
    __shared__ float tile[32][33];
    const int b = blockIdx.x, tid = threadIdx.x;
    if (b < 1856) {
        transpose_tile(w0, W0T, 1805, 1024, KP0, (b % 58) * 32, (b / 58) * 32, tile, tid);
    } else if (b < 2368) {
        int bb = b - 1856;
        transpose_tile(w1, W1T, 1024, 512, 1024, (bb % 32) * 32, (bb / 32) * 32, tile, tid);
    } else {
        int r = (b - 2368) * 256 + tid;
        NN[r] = 0.f;
        if (b == 2368 && tid <= 128) FLG[tid] = 0;   // 128 flags + ticket
    }
}

// ==================== fused gather + gemm0 (producer/consumer, 256 blocks x 512)
// bid<PBLK: producer — ZERO-REGISTER gathers via global_load_lds(4B):
//   all 64 lanes fetch emb[idx][lane] (256B contiguous) direct to this block's
//   (idle-until-worker) LDS; no destination VGPRs -> nothing for the register
//   allocator to spill (R12-R14 failure: 66 pending loads spilled to scratch,
//   scratch stores share in-order vmcnt -> serialized to 1 load/latency).
//   Per wave: 12KB LDS slice = 48 slots; batch 48 -> vmcnt(0) -> consume
//   (FM accumulate + bf16 X stores) -> lgkmcnt(0) -> batch 18 -> consume.
//   Per row: drain + release FLG[row>>7]+=1 (target 128). Fall through to worker.
// workers: ticket queue over 512 tiles (BM=128,BN=256), spin-acquire FLG[br]==128,
//   single-barrier double-buffered gemm (R8/R10-R14-proven body).
// LDS 96KB -> 1 block/CU, grid 256 = #CUs -> all co-resident (no deadlock).
__global__ __launch_bounds__(512, 2) void fused_g0(const int* __restrict__ oh,
                                                   const int* __restrict__ mh,
                                                   const float* __restrict__ fmw,
                                                   const float* __restrict__ emb,
                                                   const float* __restrict__ dense,
                                                   const __hip_bfloat16* __restrict__ W0T,
                                                   const float* __restrict__ b0,
                                                   __hip_bfloat16* __restrict__ X,
                                                   __hip_bfloat16* __restrict__ H0,
                                                   float* __restrict__ FM,
                                                   int* __restrict__ FLG) {
    __shared__ __align__(16) char lds[98304];      // worker: A[2]32K+B[2]64K; producer: 8x12KB scratch
    __shared__ int tau_sh;
    const int tid = threadIdx.x, bid = blockIdx.x;
    const int lane = tid & 63, wvi = tid >> 6;
    int* tick = FLG + 128;

    if (bid < PBLK) {
        // ---------------- producer role: zero-register LDS-direct gathers
        const int gw = bid * 8 + wvi;              // 0..1023
        char* wlds = lds + wvi * 12288;            // 48 slots x 256B
        for (int row = gw; row < NB; row += PBLK * 8) {
            const int ohi = (lane < 26) ? oh[row * 26 + lane] : 0;
            const int mhi = (lane < 40) ? mh[row * 40 + lane] : 0;
            const float fm1 = (lane < 26) ? fmw[ohi] : 0.f;
            const float dv = (lane < 13) ? dense[row * 13 + lane] : 0.f;

            // batch 1: fields 0..47 (oh 0..25, mh 0..21) -> slots 0..47
            #pragma unroll
            for (int f = 0; f < 26; ++f) {
                int idx = __shfl(ohi, f);
                load_lds4(emb + (size_t)idx * 64 + lane, wlds + f * 256);
            }
            #pragma unroll
            for (int l = 0; l < 22; ++l) {
                int idx = __shfl(mhi, l);
                load_lds4(emb + (size_t)idx * 64 + lane, wlds + (26 + l) * 256);
            }
            VMCNT(0);

            __hip_bfloat16* Xr = X + (size_t)row * KP0;
            float s = 0.f, sq = 0.f, a0 = 0.f, a1 = 0.f;
            #pragma unroll
            for (int f = 0; f < 26; ++f) {
                float x = *(const float*)(wlds + f * 256 + lane * 4);
                s += x; sq += x * x;
                Xr[f * 64 + lane] = __float2bfloat16(x);
            }
            #pragma unroll
            for (int l = 0; l < 22; ++l) {
                float x = *(const float*)(wlds + (26 + l) * 256 + lane * 4);
                if (l < 20) a0 += x; else a1 += x;
            }
            LGKM0();   // ds_reads of slots drained before batch-2 overwrites them

            // batch 2: mh 22..39 -> slots 0..17
            #pragma unroll
            for (int l = 22; l < 40; ++l) {
                int idx = __shfl(mhi, l);
                load_lds4(emb + (size_t)idx * 64 + lane, wlds + (l - 22) * 256);
            }
            VMCNT(0);
            #pragma unroll
            for (int l = 0; l < 18; ++l)
                a1 += *(const float*)(wlds + l * 256 + lane * 4);

            a0 *= 0.05f; a1 *= 0.05f;
            s += a0 + a1; sq += a0 * a0 + a1 * a1;
            Xr[26 * 64 + lane] = __float2bfloat16(a0);
            Xr[27 * 64 + lane] = __float2bfloat16(a1);
            float red = 0.5f * (s * s - sq) + fm1;
            #pragma unroll
            for (int off = 32; off; off >>= 1) red += __shfl_xor(red, off);
            if (lane == 0) FM[row] = red;
            Xr[1792 + lane] = __float2bfloat16(dv);   // 1792..1855: dense + pad
            VMCNT(0);                                  // drain X stores
            if (lane == 0)
                __hip_atomic_fetch_add(&FLG[row >> 7], 1, __ATOMIC_RELEASE,
                                       __HIP_MEMORY_SCOPE_AGENT);
            LGKM0();   // all LDS reads done before next row's batch-1 overwrites
        }
    }

    // ---------------- worker role: gemm0 tiles off the ticket queue
    const int lr = lane & 15, lg = lane >> 4;
    const int wr = wvi >> 2, wc = wvi & 3;
    const int srcx = ((tid & 7) ^ ((tid >> 3) & 7)) << 4;
    const int xr0 = (lg ^ (lr & 7)) << 4;
    const int xr1 = ((4 + lg) ^ (lr & 7)) << 4;
    const int arow = (wr * 64 + lr) * 128;
    const int brow = (wc * 64 + lr) * 128;
    const float bv = b0[0];

    while (true) {
        if (tid == 0)
            tau_sh = __hip_atomic_fetch_add(tick, 1, __ATOMIC_RELAXED, __HIP_MEMORY_SCOPE_AGENT);
        __syncthreads();
        const int tau = tau_sh;
        __syncthreads();
        if (tau >= 512) break;
        const int tbr = tau >> 2, tbc = tau & 3;
        if (tid == 0) {
            while (__hip_atomic_load(&FLG[tbr], __ATOMIC_ACQUIRE, __HIP_MEMORY_SCOPE_AGENT) < 128)
                __builtin_amdgcn_s_sleep(2);
        }
        __syncthreads();   // all waves see fresh X; LDS safe vs previous tile

        const char* Ab = (const char*)X + (size_t)(tbr * 128) * (KP0 * 2);
        const char* Bb = (const char*)W0T + (size_t)(tbc * 256) * (KP0 * 2);
        auto stA = [&](int tt, int c) {
            int gr = c * 64 + (tid >> 3);
            load_lds16(Ab + (size_t)gr * (KP0 * 2) + (size_t)tt * 128 + srcx,
                       &lds[(tt & 1) * 16384 + c * 8192 + wvi * 1024]);
        };
        auto stB = [&](int tt, int c) {
            int gr = c * 64 + (tid >> 3);
            load_lds16(Bb + (size_t)gr * (KP0 * 2) + (size_t)tt * 128 + srcx,
                       &lds[32768 + (tt & 1) * 32768 + c * 8192 + wvi * 1024]);
        };

        f32x4 acc[4][4] = {};

        stA(0, 0); stA(0, 1);
        stB(0, 0); stB(0, 1); stB(0, 2); stB(0, 3);
        VMCNT(0);
        SBAR0();
        __builtin_amdgcn_s_barrier();

        for (int t = 0; t < 29; ++t) {
            if (t + 1 < 29) {
                stA(t + 1, 0); stA(t + 1, 1);
                stB(t + 1, 0); stB(t + 1, 1); stB(t + 1, 2); stB(t + 1, 3);
            }
            SBAR0();
            const char* LA = &lds[(t & 1) * 16384];
            const char* LB = &lds[32768 + (t & 1) * 32768];
            bf16x8 a[4][2], b[4][2];
            #pragma unroll
            for (int m = 0; m < 4; ++m) {
                a[m][0] = *(const bf16x8*)(LA + arow + m * 2048 + xr0);
                a[m][1] = *(const bf16x8*)(LA + arow + m * 2048 + xr1);
            }
            #pragma unroll
            for (int n = 0; n < 2; ++n) {
                b[n][0] = *(const bf16x8*)(LB + brow + n * 2048 + xr0);
                b[n][1] = *(const bf16x8*)(LB + brow + n * 2048 + xr1);
            }
            __builtin_amdgcn_s_setprio(1);
            #pragma unroll
            for (int m = 0; m < 4; ++m)
                #pragma unroll
                for (int n = 0; n < 2; ++n)
                    #pragma unroll
                    for (int kk = 0; kk < 2; ++kk)
                        acc[m][n] = __builtin_amdgcn_mfma_f32_16x16x32_bf16(a[m][kk], b[n][kk], acc[m][n], 0, 0, 0);
            __builtin_amdgcn_s_setprio(0);
            #pragma unroll
            for (int n = 2; n < 4; ++n) {
                b[n][0] = *(const bf16x8*)(LB + brow + n * 2048 + xr0);
                b[n][1] = *(const bf16x8*)(LB + brow + n * 2048 + xr1);
            }
            __builtin_amdgcn_s_setprio(1);
            #pragma unroll
            for (int m = 0; m < 4; ++m)
                #pragma unroll
                for (int n = 2; n < 4; ++n)
                    #pragma unroll
                    for (int kk = 0; kk < 2; ++kk)
                        acc[m][n] = __builtin_amdgcn_mfma_f32_16x16x32_bf16(a[m][kk], b[n][kk], acc[m][n], 0, 0, 0);
            __builtin_amdgcn_s_setprio(0);
            SBAR0();
            if (t + 1 < 29) {
                VMCNT(0);
                __builtin_amdgcn_s_barrier();
            }
        }

        const int rowb = tbr * 128 + wr * 64, colb = tbc * 256 + wc * 64;
        #pragma unroll
        for (int m = 0; m < 4; ++m)
            #pragma unroll
            for (int n = 0; n < 4; ++n)
                #pragma unroll
                for (int r = 0; r < 4; ++r) {
                    int row = rowb + m * 16 + lg * 4 + r;
                    int col = colb + n * 16 + lr;
                    H0[(size_t)row * 1024 + col] = __float2bfloat16(fmaxf(acc[m][n][r] + bv, 0.f));
                }
    }
}

// ==================== GEMM1 (single-barrier db, fused w2 dot) — R8 proven
template<int NREP, bool FUSED>
__global__ __launch_bounds__(512, 2) void gemm_db(const __hip_bfloat16* __restrict__ A,
                                                  const __hip_bfloat16* __restrict__ BT,
                                                  const float* __restrict__ bias,
                                                  __hip_bfloat16* __restrict__ C,
                                                  const float* __restrict__ w2,
                                                  float* __restrict__ NN,
                                                  int M, int N, int K) {
    constexpr int BREG = NREP * 8192;
    constexpr int NLO  = (NREP == 4) ? 2 : 1;
    __shared__ __align__(16) char lds[65536 + 2 * BREG];

    const int tid = threadIdx.x;
    const int wv = tid >> 6, lane = tid & 63;
    const int lr = lane & 15, lg = lane >> 4;
    const int wr = wv >> 2, wc = wv & 3;

    const int bid = blockIdx.x;
    const int wg = (bid & 7) * 32 + (bid >> 3);
    const int br = wg >> 2, bc = wg & 3;

    const size_t rowBytes = (size_t)K * 2;
    const char* Ab = (const char*)A + (size_t)(br * 256) * rowBytes;
    const char* Bb = (const char*)BT + (size_t)(bc * (NREP * 64)) * rowBytes;
    const int nt = K >> 6;

    const int srcx = ((tid & 7) ^ ((tid >> 3) & 7)) << 4;
    auto stA = [&](int tt, int c) {
        int gr = c * 64 + (tid >> 3);
        load_lds16(Ab + (size_t)gr * rowBytes + (size_t)tt * 128 + srcx,
                   &lds[(tt & 1) * 32768 + c * 8192 + wv * 1024]);
    };
    auto stB = [&](int tt, int c) {
        int gr = c * 64 + (tid >> 3);
        load_lds16(Bb + (size_t)gr * rowBytes + (size_t)tt * 128 + srcx,
                   &lds[65536 + (tt & 1) * BREG + c * 8192 + wv * 1024]);
    };

    f32x4 acc[8][NREP] = {};

    #pragma unroll
    for (int c = 0; c < 4; ++c) stA(0, c);
    #pragma unroll
    for (int c = 0; c < NREP; ++c) stB(0, c);
    VMCNT(0);
    SBAR0();
    __builtin_amdgcn_s_barrier();

    const int xr0 = (lg ^ (lr & 7)) << 4;
    const int xr1 = ((4 + lg) ^ (lr & 7)) << 4;
    const int arow = (wr * 128 + lr) * 128;
    const int brow = (wc * (NREP * 16) + lr) * 128;

    for (int t = 0; t < nt; ++t) {
        if (t + 1 < nt) {
            #pragma unroll
            for (int c = 0; c < 4; ++c) stA(t + 1, c);
            #pragma unroll
            for (int c = 0; c < NREP; ++c) stB(t + 1, c);
        }
        SBAR0();

        const char* LA = &lds[(t & 1) * 32768];
        const char* LB = &lds[65536 + (t & 1) * BREG];
        bf16x8 a1[4][2], a2[4][2], bl[NLO][2], bh[NLO][2];

        #pragma unroll
        for (int m = 0; m < 4; ++m) {
            a1[m][0] = *(const bf16x8*)(LA + arow + m * 2048 + xr0);
            a1[m][1] = *(const bf16x8*)(LA + arow + m * 2048 + xr1);
        }
        #pragma unroll
        for (int n = 0; n < NLO; ++n) {
            bl[n][0] = *(const bf16x8*)(LB + brow + n * 2048 + xr0);
            bl[n][1] = *(const bf16x8*)(LB + brow + n * 2048 + xr1);
        }
        __builtin_amdgcn_s_setprio(1);
        #pragma unroll
        for (int m = 0; m < 4; ++m)
            #pragma unroll
            for (int n = 0; n < NLO; ++n)
                #pragma unroll
                for (int kk = 0; kk < 2; ++kk)
                    acc[m][n] = __builtin_amdgcn_mfma_f32_16x16x32_bf16(a1[m][kk], bl[n][kk], acc[m][n], 0, 0, 0);
        __builtin_amdgcn_s_setprio(0);

        #pragma unroll
        for (int m = 0; m < 4; ++m) {
            a2[m][0] = *(const bf16x8*)(LA + arow + (4 + m) * 2048 + xr0);
            a2[m][1] = *(const bf16x8*)(LA + arow + (4 + m) * 2048 + xr1);
        }
        __builtin_amdgcn_s_setprio(1);
        #pragma unroll
        for (int m = 0; m < 4; ++m)
            #pragma unroll
            for (int n = 0; n < NLO; ++n)
                #pragma unroll
                for (int kk = 0; kk < 2; ++kk)
                    acc[4 + m][n] = __builtin_amdgcn_mfma_f32_16x16x32_bf16(a2[m][kk], bl[n][kk], acc[4 + m][n], 0, 0, 0);
        __builtin_amdgcn_s_setprio(0);

        #pragma unroll
        for (int n = 0; n < NLO; ++n) {
            bh[n][0] = *(const bf16x8*)(LB + brow + (NLO + n) * 2048 + xr0);
            bh[n][1] = *(const bf16x8*)(LB + brow + (NLO + n) * 2048 + xr1);
        }
        __builtin_amdgcn_s_setprio(1);
        #pragma unroll
        for (int m = 0; m < 4; ++m)
            #pragma unroll
            for (int n = 0; n < NLO; ++n)
                #pragma unroll
                for (int kk = 0; kk < 2; ++kk)
                    acc[m][NLO + n] = __builtin_amdgcn_mfma_f32_16x16x32_bf16(a1[m][kk], bh[n][kk], acc[m][NLO + n], 0, 0, 0);
        __builtin_amdgcn_s_setprio(0);

        __builtin_amdgcn_s_setprio(1);
        #pragma unroll
        for (int m = 0; m < 4; ++m)
            #pragma unroll
            for (int n = 0; n < NLO; ++n)
                #pragma unroll
                for (int kk = 0; kk < 2; ++kk)
                    acc[4 + m][NLO + n] = __builtin_amdgcn_mfma_f32_16x16x32_bf16(a2[m][kk], bh[n][kk], acc[4 + m][NLO + n], 0, 0, 0);
        __builtin_amdgcn_s_setprio(0);

        SBAR0();
        if (t + 1 < nt) {
            VMCNT(0);
            __builtin_amdgcn_s_barrier();
        }
    }

    const float bv = bias[0];
    const int rowb = br * 256 + wr * 128, colb = bc * (NREP * 64) + wc * (NREP * 16);
    if constexpr (FUSED) {
        float w2v[NREP];
        #pragma unroll
        for (int n = 0; n < NREP; ++n) w2v[n] = w2[colb + n * 16 + lr];
        #pragma unroll
        for (int m = 0; m < 8; ++m)
            #pragma unroll
            for (int r = 0; r < 4; ++r) {
                float p = 0.f;
                #pragma unroll
                for (int n = 0; n < NREP; ++n)
                    p += fmaxf(acc[m][n][r] + bv, 0.f) * w2v[n];
                #pragma unroll
                for (int off = 8; off; off >>= 1) p += __shfl_xor(p, off);
                if (lr == 0)
                    atomicAdd(&NN[rowb + m * 16 + lg * 4 + r], p);
            }
    } else {
        #pragma unroll
        for (int m = 0; m < 8; ++m)
            #pragma unroll
            for (int n = 0; n < NREP; ++n)
                #pragma unroll
                for (int r = 0; r < 4; ++r) {
                    int row = rowb + m * 16 + lg * 4 + r;
                    int col = colb + n * 16 + lr;
                    C[(size_t)row * N + col] = __float2bfloat16(fmaxf(acc[m][n][r] + bv, 0.f));
                }
    }
}

// ==================== finish: out = sigmoid(FM + relu(NN + b2))
__global__ __launch_bounds__(256) void finish_k(const float* __restrict__ NN,
                                                const float* __restrict__ b2,
                                                const float* __restrict__ FM,
                                                float* __restrict__ out) {
    const int row = blockIdx.x * 256 + threadIdx.x;
    float v = fmaxf(NN[row] + b2[0], 0.f) + FM[row];
    out[row] = 1.f / (1.f + expf(-v));
}

extern "C" void kernel_launch(void* const* d_in, const int* in_sizes, int n_in,
                              void* d_out, int out_size, void* d_ws, size_t ws_size,
                              hipStream_t stream) {
    const float* dense    = (const float*)d_in[0];
    const int*   onehot   = (const int*)d_in[1];
    const int*   multihot = (const int*)d_in[2];
    const float* fm_w     = (const float*)d_in[3];
    const float* fm_emb   = (const float*)d_in[4];
    const float* w0       = (const float*)d_in[5];
    const float* b0       = (const float*)d_in[6];
    const float* w1       = (const float*)d_in[7];
    const float* b1       = (const float*)d_in[8];
    const float* w2       = (const float*)d_in[9];
    const float* b2       = (const float*)d_in[10];
    float* out = (float*)d_out;

    char* ws = (char*)d_ws;
    __hip_bfloat16* X   = (__hip_bfloat16*)(ws + OFF_X);
    __hip_bfloat16* H0  = (__hip_bfloat16*)(ws + OFF_H0);
    __hip_bfloat16* W0T = (__hip_bfloat16*)(ws + OFF_W0T);
    __hip_bfloat16* W1T = (__hip_bfloat16*)(ws + OFF_W1T);
    float*          FM  = (float*)(ws + OFF_FM);
    float*          NN  = (float*)(ws + OFF_NN);
    int*            FLG = (int*)(ws + OFF_FLAG);

    prep<<<2432, 256, 0, stream>>>(w0, w1, W0T, W1T, NN, FLG);
    fused_g0<<<256, 512, 0, stream>>>(onehot, multihot, fm_w, fm_emb, dense,
                                      W0T, b0, X, H0, FM, FLG);
    gemm_db<2, true><<<256, 512, 0, stream>>>(H0, W1T, b1, nullptr, w2, NN,
                                              NB, 512, 1024);
    finish_k<<<64, 256, 0, stream>>>(NN, b2, FM, out);
}

// Round 16
// 165.577 us; speedup vs baseline: 4.9809x; 4.9258x over previous
//
#include <hip/hip_runtime.h>
#include <hip/hip_bf16.h>
#include <math.h>

typedef __attribute__((ext_vector_type(8))) short bf16x8;
typedef __attribute__((ext_vector_type(4))) float f32x4;

typedef void __attribute__((address_space(1))) gvoid_t;
typedef void __attribute__((address_space(3))) lvoid_t;

#define KP0   1856          // NN_IN (1805) padded to multiple of 64
#define NB    16384
// workspace layout (bytes)
#define OFF_X    0u
#define OFF_H0   60817408u  // 16384*1856*2
#define OFF_W0T  94371840u  // +16384*1024*2
#define OFF_W1T  98172928u  // +1856*1024*2
#define OFF_FM   99221504u  // +512*1024*2
#define OFF_NN   99287040u  // +16384*4

#define VMCNT(n) asm volatile("s_waitcnt vmcnt(" #n ")" ::: "memory")
#define SBAR0()  __builtin_amdgcn_sched_barrier(0)

__device__ __forceinline__ float bf2f(short s) {
    return __uint_as_float(((unsigned)(unsigned short)s) << 16);
}

__device__ __forceinline__ void load_lds16(const void* g, void* l) {
    __builtin_amdgcn_global_load_lds(
        (gvoid_t*)(uintptr_t)g,
        (lvoid_t*)(unsigned)(uintptr_t)l,
        16, 0, 0);
}

// ---------------- merged prep: gather+FM+zero-NN (blocks 0..4095), w0 transpose
//                  (next 1856), w1 transpose (next 512). 256 threads/block.
__device__ __forceinline__ void transpose_tile(const float* __restrict__ W,
                                               __hip_bfloat16* __restrict__ WT,
                                               int K, int N, int KP, int k0, int n0,
                                               float (*tile)[33], int tid) {
    const int tx = tid & 31, ty = tid >> 5;
    #pragma unroll
    for (int i = 0; i < 32; i += 8) {
        int k = k0 + ty + i;
        tile[ty + i][tx] = (k < K) ? W[(size_t)k * N + (n0 + tx)] : 0.f;
    }
    __syncthreads();
    #pragma unroll
    for (int i = 0; i < 32; i += 8) {
        int n = n0 + ty + i, k = k0 + tx;
        WT[(size_t)n * KP + k] = __float2bfloat16(tile[tx][ty + i]);
    }
}

__global__ __launch_bounds__(256) void prep(const float* __restrict__ dense,
                                            const int* __restrict__ onehot,
                                            const int* __restrict__ multihot,
                                            const float* __restrict__ fm_w,
                                            const float* __restrict__ fm_emb,
                                            const float* __restrict__ w0,
                                            const float* __restrict__ w1,
                                            __hip_bfloat16* __restrict__ X,
                                            float* __restrict__ FM,
                                            float* __restrict__ NN,
                                            __hip_bfloat16* __restrict__ W0T,
                                            __hip_bfloat16* __restrict__ W1T) {
    __shared__ float tile[32][33];
    const int b = blockIdx.x, tid = threadIdx.x;
    if (b >= 4096) {
        if (b < 4096 + 1856) {
            int bb = b - 4096;
            transpose_tile(w0, W0T, 1805, 1024, KP0, (bb % 58) * 32, (bb / 58) * 32, tile, tid);
        } else {
            int bb = b - 5952;
            transpose_tile(w1, W1T, 1024, 512, 1024, (bb % 32) * 32, (bb / 32) * 32, tile, tid);
        }
        return;
    }
    const int wv = tid >> 6, lane = tid & 63;
    const int row = b * 4 + wv;
    const int oh = (lane < 26) ? onehot[row * 26 + lane] : 0;
    const int mh = (lane < 40) ? multihot[row * 40 + lane] : 0;
    const float fm1 = (lane < 26) ? fm_w[oh] : 0.f;
    __hip_bfloat16* Xr = X + (size_t)row * KP0;
    float s = 0.f, sq = 0.f;
    for (int f = 0; f < 26; ++f) {
        int idx = __shfl(oh, f);
        float v = fm_emb[(size_t)idx * 64 + lane];
        s += v; sq += v * v;
        Xr[f * 64 + lane] = __float2bfloat16(v);
    }
    #pragma unroll
    for (int h = 0; h < 2; ++h) {
        float a = 0.f;
        for (int l = 0; l < 20; ++l) {
            int idx = __shfl(mh, h * 20 + l);
            a += fm_emb[(size_t)idx * 64 + lane];
        }
        float v = a * (1.f / 20.f);
        s += v; sq += v * v;
        Xr[(26 + h) * 64 + lane] = __float2bfloat16(v);
    }
    float red = 0.5f * (s * s - sq) + fm1;
    #pragma unroll
    for (int off = 32; off; off >>= 1) red += __shfl_xor(red, off);
    if (lane == 0) FM[row] = red;
    if (lane == 32) NN[row] = 0.f;
    float dv = (lane < 13) ? dense[row * 13 + lane] : 0.f;
    Xr[1792 + lane] = __float2bfloat16(dv);   // rows 1792..1855: dense + zero pad
}

// ---------------- single-barrier double-buffered GEMM
// C(MxN,bf16) = relu(A(MxK)*BT(NxK)^T + bias). BM=256, BN=NREP*64, BK=64.
// 8 waves (2M x 4N), wave tile 128 x NREP*16. Regions: A[2] 32KB, B[2] NREP*8KB.
// Stage tile t+1 (other buffer) at tile top; ONE vmcnt(0)+barrier per tile at
// bottom. LDS rows 128B, 16B-slot XOR swizzle (slot ^= row&7) both-sides.
// FUSED: accumulate relu(C+bias)*w2[col] into NN[row] (atomic) instead of storing C.
// Requires: M%256==0, grid=(M/256)*(N/BN) with N/BN==4, K%64==0, K/64>=2.
template<int NREP, bool FUSED>
__global__ __launch_bounds__(512, 2) void gemm_db(const __hip_bfloat16* __restrict__ A,
                                                  const __hip_bfloat16* __restrict__ BT,
                                                  const float* __restrict__ bias,
                                                  __hip_bfloat16* __restrict__ C,
                                                  const float* __restrict__ w2,
                                                  float* __restrict__ NN,
                                                  int M, int N, int K) {
    constexpr int BREG = NREP * 8192;              // one B region
    constexpr int NLO  = (NREP == 4) ? 2 : 1;
    __shared__ __align__(16) char lds[65536 + 2 * BREG];   // A[2]:64KB + B[2]

    const int tid = threadIdx.x;
    const int wv = tid >> 6, lane = tid & 63;
    const int lr = lane & 15, lg = lane >> 4;
    const int wr = wv >> 2, wc = wv & 3;

    const int bid = blockIdx.x;                    // XCD-chunked swizzle, grid == 256
    const int wg = (bid & 7) * 32 + (bid >> 3);
    const int br = wg >> 2, bc = wg & 3;

    const size_t rowBytes = (size_t)K * 2;
    const char* Ab = (const char*)A + (size_t)(br * 256) * rowBytes;
    const char* Bb = (const char*)BT + (size_t)(bc * (NREP * 64)) * rowBytes;
    const int nt = K >> 6;

    const int srcx = ((tid & 7) ^ ((tid >> 3) & 7)) << 4;   // source-side slot swizzle
    auto stA = [&](int tt, int c) {
        int gr = c * 64 + (tid >> 3);
        load_lds16(Ab + (size_t)gr * rowBytes + (size_t)tt * 128 + srcx,
                   &lds[(tt & 1) * 32768 + c * 8192 + wv * 1024]);
    };
    auto stB = [&](int tt, int c) {
        int gr = c * 64 + (tid >> 3);
        load_lds16(Bb + (size_t)gr * rowBytes + (size_t)tt * 128 + srcx,
                   &lds[65536 + (tt & 1) * BREG + c * 8192 + wv * 1024]);
    };

    f32x4 acc[8][NREP] = {};

    // prologue: stage tile 0, drain, barrier
    #pragma unroll
    for (int c = 0; c < 4; ++c) stA(0, c);
    #pragma unroll
    for (int c = 0; c < NREP; ++c) stB(0, c);
    VMCNT(0);
    SBAR0();
    __builtin_amdgcn_s_barrier();

    const int xr0 = (lg ^ (lr & 7)) << 4;          // read-side slot swizzle, kk=0
    const int xr1 = ((4 + lg) ^ (lr & 7)) << 4;    // kk=1
    const int arow = (wr * 128 + lr) * 128;
    const int brow = (wc * (NREP * 16) + lr) * 128;

    for (int t = 0; t < nt; ++t) {
        // ---- stage t+1 at tile top (full tile of latency to land)
        if (t + 1 < nt) {
            #pragma unroll
            for (int c = 0; c < 4; ++c) stA(t + 1, c);
            #pragma unroll
            for (int c = 0; c < NREP; ++c) stB(t + 1, c);
        }
        SBAR0();   // pin load issues before the read/MFMA body

        const char* LA = &lds[(t & 1) * 32768];
        const char* LB = &lds[65536 + (t & 1) * BREG];
        bf16x8 a1[4][2], a2[4][2], bl[NLO][2], bh[NLO][2];

        // ---- chunk 1: a0-3 + b-lo; MFMA m0-3 x n-lo
        #pragma unroll
        for (int m = 0; m < 4; ++m) {
            a1[m][0] = *(const bf16x8*)(LA + arow + m * 2048 + xr0);
            a1[m][1] = *(const bf16x8*)(LA + arow + m * 2048 + xr1);
        }
        #pragma unroll
        for (int n = 0; n < NLO; ++n) {
            bl[n][0] = *(const bf16x8*)(LB + brow + n * 2048 + xr0);
            bl[n][1] = *(const bf16x8*)(LB + brow + n * 2048 + xr1);
        }
        __builtin_amdgcn_s_setprio(1);
        #pragma unroll
        for (int m = 0; m < 4; ++m)
            #pragma unroll
            for (int n = 0; n < NLO; ++n)
                #pragma unroll
                for (int kk = 0; kk < 2; ++kk)
                    acc[m][n] = __builtin_amdgcn_mfma_f32_16x16x32_bf16(a1[m][kk], bl[n][kk], acc[m][n], 0, 0, 0);
        __builtin_amdgcn_s_setprio(0);

        // ---- chunk 2: a4-7; MFMA m4-7 x n-lo
        #pragma unroll
        for (int m = 0; m < 4; ++m) {
            a2[m][0] = *(const bf16x8*)(LA + arow + (4 + m) * 2048 + xr0);
            a2[m][1] = *(const bf16x8*)(LA + arow + (4 + m) * 2048 + xr1);
        }
        __builtin_amdgcn_s_setprio(1);
        #pragma unroll
        for (int m = 0; m < 4; ++m)
            #pragma unroll
            for (int n = 0; n < NLO; ++n)
                #pragma unroll
                for (int kk = 0; kk < 2; ++kk)
                    acc[4 + m][n] = __builtin_amdgcn_mfma_f32_16x16x32_bf16(a2[m][kk], bl[n][kk], acc[4 + m][n], 0, 0, 0);
        __builtin_amdgcn_s_setprio(0);

        // ---- chunk 3: b-hi; MFMA m0-3 x n-hi
        #pragma unroll
        for (int n = 0; n < NLO; ++n) {
            bh[n][0] = *(const bf16x8*)(LB + brow + (NLO + n) * 2048 + xr0);
            bh[n][1] = *(const bf16x8*)(LB + brow + (NLO + n) * 2048 + xr1);
        }
        __builtin_amdgcn_s_setprio(1);
        #pragma unroll
        for (int m = 0; m < 4; ++m)
            #pragma unroll
            for (int n = 0; n < NLO; ++n)
                #pragma unroll
                for (int kk = 0; kk < 2; ++kk)
                    acc[m][NLO + n] = __builtin_amdgcn_mfma_f32_16x16x32_bf16(a1[m][kk], bh[n][kk], acc[m][NLO + n], 0, 0, 0);
        __builtin_amdgcn_s_setprio(0);

        // ---- chunk 4: MFMA m4-7 x n-hi
        __builtin_amdgcn_s_setprio(1);
        #pragma unroll
        for (int m = 0; m < 4; ++m)
            #pragma unroll
            for (int n = 0; n < NLO; ++n)
                #pragma unroll
                for (int kk = 0; kk < 2; ++kk)
                    acc[4 + m][NLO + n] = __builtin_amdgcn_mfma_f32_16x16x32_bf16(a2[m][kk], bh[n][kk], acc[4 + m][NLO + n], 0, 0, 0);
        __builtin_amdgcn_s_setprio(0);

        // ---- tile end: wait stage(t+1) landed, sync
        SBAR0();
        if (t + 1 < nt) {
            VMCNT(0);
            __builtin_amdgcn_s_barrier();
        }
    }

    const float bv = bias[0];
    const int rowb = br * 256 + wr * 128, colb = bc * (NREP * 64) + wc * (NREP * 16);
    if constexpr (FUSED) {
        float w2v[NREP];
        #pragma unroll
        for (int n = 0; n < NREP; ++n) w2v[n] = w2[colb + n * 16 + lr];
        #pragma unroll
        for (int m = 0; m < 8; ++m)
            #pragma unroll
            for (int r = 0; r < 4; ++r) {
                float p = 0.f;
                #pragma unroll
                for (int n = 0; n < NREP; ++n)
                    p += fmaxf(acc[m][n][r] + bv, 0.f) * w2v[n];
                #pragma unroll
                for (int off = 8; off; off >>= 1) p += __shfl_xor(p, off);
                if (lr == 0)
                    atomicAdd(&NN[rowb + m * 16 + lg * 4 + r], p);
            }
    } else {
        #pragma unroll
        for (int m = 0; m < 8; ++m)
            #pragma unroll
            for (int n = 0; n < NREP; ++n)
                #pragma unroll
                for (int r = 0; r < 4; ++r) {
                    int row = rowb + m * 16 + lg * 4 + r;
                    int col = colb + n * 16 + lr;
                    C[(size_t)row * N + col] = __float2bfloat16(fmaxf(acc[m][n][r] + bv, 0.f));
                }
    }
}

// ---------------- finish: out = sigmoid(FM + relu(NN + b2))
__global__ __launch_bounds__(256) void finish_k(const float* __restrict__ NN,
                                                const float* __restrict__ b2,
                                                const float* __restrict__ FM,
                                                float* __restrict__ out) {
    const int row = blockIdx.x * 256 + threadIdx.x;
    float v = fmaxf(NN[row] + b2[0], 0.f) + FM[row];
    out[row] = 1.f / (1.f + expf(-v));
}

extern "C" void kernel_launch(void* const* d_in, const int* in_sizes, int n_in,
                              void* d_out, int out_size, void* d_ws, size_t ws_size,
                              hipStream_t stream) {
    const float* dense    = (const float*)d_in[0];
    const int*   onehot   = (const int*)d_in[1];
    const int*   multihot = (const int*)d_in[2];
    const float* fm_w     = (const float*)d_in[3];
    const float* fm_emb   = (const float*)d_in[4];
    const float* w0       = (const float*)d_in[5];
    const float* b0       = (const float*)d_in[6];
    const float* w1       = (const float*)d_in[7];
    const float* b1       = (const float*)d_in[8];
    const float* w2       = (const float*)d_in[9];
    const float* b2       = (const float*)d_in[10];
    float* out = (float*)d_out;

    char* ws = (char*)d_ws;
    __hip_bfloat16* X   = (__hip_bfloat16*)(ws + OFF_X);
    __hip_bfloat16* H0  = (__hip_bfloat16*)(ws + OFF_H0);
    __hip_bfloat16* W0T = (__hip_bfloat16*)(ws + OFF_W0T);
    __hip_bfloat16* W1T = (__hip_bfloat16*)(ws + OFF_W1T);
    float*          FM  = (float*)(ws + OFF_FM);
    float*          NN  = (float*)(ws + OFF_NN);

    prep<<<6464, 256, 0, stream>>>(dense, onehot, multihot, fm_w, fm_emb, w0, w1,
                                   X, FM, NN, W0T, W1T);
    gemm_db<4, false><<<256, 512, 0, stream>>>(X,  W0T, b0, H0, nullptr, nullptr,
                                               NB, 1024, KP0);   // 64x4, 256x256
    gemm_db<2, true><<<256, 512, 0, stream>>>(H0, W1T, b1, nullptr, w2, NN,
                                              NB, 512, 1024);    // 64x4, 256x128, fused dot
    finish_k<<<64, 256, 0, stream>>>(NN, b2, FM, out);
}